// Round 2
// baseline (284.753 us; speedup 1.0000x reference)
//
#include <hip/hip_runtime.h>
#include <stdint.h>

typedef __bf16 bf16_t;
typedef __bf16 bf16x8 __attribute__((ext_vector_type(8)));
typedef float f32x4 __attribute__((ext_vector_type(4)));

// async global->LDS, 16B per lane; LDS dest is wave-uniform base + lane*16
__device__ __forceinline__ void gload_lds16(const void* g, void* l) {
  __builtin_amdgcn_global_load_lds(
      (const __attribute__((address_space(1))) uint32_t*)g,
      (__attribute__((address_space(3))) uint32_t*)l, 16, 0, 0);
}

// ---------------- cast f32 -> bf16 (vectorized) ----------------
__global__ void cast_f32_bf16(const float* __restrict__ in,
                              bf16_t* __restrict__ out, int n4) {
  int i = blockIdx.x * blockDim.x + threadIdx.x;
  int stride = gridDim.x * blockDim.x;
  for (int idx = i; idx < n4; idx += stride) {
    float4 v = reinterpret_cast<const float4*>(in)[idx];
    union { bf16_t b[4]; uint2 u; } pk;
    pk.b[0] = (bf16_t)v.x; pk.b[1] = (bf16_t)v.y;
    pk.b[2] = (bf16_t)v.z; pk.b[3] = (bf16_t)v.w;
    reinterpret_cast<uint2*>(out)[idx] = pk.u;
  }
}

// ---------------- pipelined GEMM: C[M][N] = A[M][K] * B[N][K]^T (+bias) -----
// BM=256 BN=128 BK=64, K=1024 fixed (NT=16). 8 waves (2M x 4N), per-wave
// 128x32 out = 8x2 frags of 16x16x32 bf16 MFMA.
// 3-slot LDS ring (144KB), staged 2 tiles ahead; steady-state s_waitcnt
// vmcnt(6); raw s_barrier once per K-tile; setprio around MFMA cluster.
// LDS rows [r][64k] chunk-swizzled: LDS[r][c] = global[r][c ^ (r&7)]
// (inverse-swizzle on global source, swizzle on ds_read -> 2-way banks, free)
template <bool BF16_OUT>
__global__ __launch_bounds__(512, 2)
void gemm_pipe(const bf16_t* __restrict__ A, const bf16_t* __restrict__ B,
               void* __restrict__ Cout, const float* __restrict__ bias,
               int N, int nbx) {
  constexpr int K = 1024, NT = 16;
  __shared__ bf16_t Al[3][256 * 64];  // 3 x 32KB
  __shared__ bf16_t Bl[3][128 * 64];  // 3 x 16KB

  const int tid = threadIdx.x;
  const int l = tid & 63, w = tid >> 6;
  const int wm = w >> 2, wn = w & 3;

  // XCD-aware swizzle (grid % 8 == 0 for all our shapes)
  const int nwg = gridDim.x;
  const int bid = blockIdx.x;
  const int swz = (bid & 7) * (nwg >> 3) + (bid >> 3);
  const int bx = swz % nbx, by = swz / nbx;
  const int m0 = bx * 256, n0 = by * 128;

  // ---- staging geometry (per thread: 4 A-chunks + 2 B-chunks of 16B) ----
  // issue i, thread t: LDS byte X = i*8192 + t*16 -> row = i*64 + t/8,
  // lds chunk = t&7 ; holds global chunk (t&7) ^ (row&7)
  const int ra = tid >> 3;                       // row-within-64-group
  const int ca = ((tid & 7) ^ (ra & 7)) * 8;     // pre-swizzled global k-chunk
  const bf16_t* pA0 = A + (size_t)(m0 +   0 + ra) * K + ca;
  const bf16_t* pA1 = A + (size_t)(m0 +  64 + ra) * K + ca;
  const bf16_t* pA2 = A + (size_t)(m0 + 128 + ra) * K + ca;
  const bf16_t* pA3 = A + (size_t)(m0 + 192 + ra) * K + ca;
  const bf16_t* pB0 = B + (size_t)(n0 +   0 + ra) * K + ca;
  const bf16_t* pB1 = B + (size_t)(n0 +  64 + ra) * K + ca;
  const int wb = w * 512;  // wave's 1KB segment (elems) within an 8KB issue

#define STAGE(t_, s_) do {                                   \
    const int kt_ = (t_) * 64;                               \
    gload_lds16(pA0 + kt_, &Al[s_][0 * 4096 + wb]);          \
    gload_lds16(pA1 + kt_, &Al[s_][1 * 4096 + wb]);          \
    gload_lds16(pA2 + kt_, &Al[s_][2 * 4096 + wb]);          \
    gload_lds16(pA3 + kt_, &Al[s_][3 * 4096 + wb]);          \
    gload_lds16(pB0 + kt_, &Bl[s_][0 * 4096 + wb]);          \
    gload_lds16(pB1 + kt_, &Bl[s_][1 * 4096 + wb]);          \
  } while (0)

  // ---- fragment-read offsets (elems). row&7 == l&7 for all frag rows. ----
  const int abase = (wm * 128 + (l & 15)) * 64;
  const int bbase = (wn * 32 + (l & 15)) * 64;
  const int ck0 = (((l >> 4) + 0) ^ (l & 7)) * 8;  // kstep 0 swizzled chunk
  const int ck1 = (((l >> 4) + 4) ^ (l & 7)) * 8;  // kstep 1 swizzled chunk

  f32x4 acc[8][2] = {};

  STAGE(0, 0);
  STAGE(1, 1);

  int slot = 0;
  for (int t = 0; t < NT; ++t) {
    // counted wait: tile t's 6 loads (issued at t-2) done; tile t+1's 6 may fly
    if (t < NT - 1) asm volatile("s_waitcnt vmcnt(6)" ::: "memory");
    else            asm volatile("s_waitcnt vmcnt(0)" ::: "memory");
    __builtin_amdgcn_s_barrier();
    asm volatile("" ::: "memory");
    if (t + 2 < NT) {
      int s2 = slot + 2; if (s2 >= 3) s2 -= 3;
      STAGE(t + 2, s2);  // slot of tile t-1: all its reads drained pre-barrier
    }
    const bf16_t* As = Al[slot];
    const bf16_t* Bs = Bl[slot];
#pragma unroll
    for (int s = 0; s < 2; ++s) {
      const int ck = s ? ck1 : ck0;
      bf16x8 af[8], bfr[2];
#pragma unroll
      for (int i = 0; i < 8; ++i)
        af[i] = *reinterpret_cast<const bf16x8*>(&As[abase + i * 1024 + ck]);
#pragma unroll
      for (int j = 0; j < 2; ++j)
        bfr[j] = *reinterpret_cast<const bf16x8*>(&Bs[bbase + j * 1024 + ck]);
      __builtin_amdgcn_s_setprio(1);
#pragma unroll
      for (int i = 0; i < 8; ++i)
#pragma unroll
        for (int j = 0; j < 2; ++j)
          acc[i][j] = __builtin_amdgcn_mfma_f32_16x16x32_bf16(af[i], bfr[j],
                                                              acc[i][j], 0, 0, 0);
      __builtin_amdgcn_s_setprio(0);
    }
    slot = (slot == 2) ? 0 : slot + 1;
  }
#undef STAGE

  // ---- epilogue: C/D layout col = lane&15, row = (lane>>4)*4 + reg ----
  const int r0 = m0 + wm * 128 + (l >> 4) * 4;
  const int c0 = n0 + wn * 32 + (l & 15);
  if (BF16_OUT) {
    bf16_t* C = (bf16_t*)Cout;
#pragma unroll
    for (int i = 0; i < 8; ++i)
#pragma unroll
      for (int j = 0; j < 2; ++j)
#pragma unroll
        for (int r = 0; r < 4; ++r)
          C[(size_t)(r0 + i * 16 + r) * N + (c0 + j * 16)] = (bf16_t)acc[i][j][r];
  } else {
    float* C = (float*)Cout;
#pragma unroll
    for (int i = 0; i < 8; ++i)
#pragma unroll
      for (int j = 0; j < 2; ++j)
#pragma unroll
        for (int r = 0; r < 4; ++r)
          C[(size_t)(r0 + i * 16 + r) * N + (c0 + j * 16)] =
              acc[i][j][r] + bias[c0 + j * 16];
  }
}

// ---------------- per-token head-attention ----------------
__global__ __launch_bounds__(256)
void attn_heads(const bf16_t* __restrict__ qkv, bf16_t* __restrict__ out) {
  __shared__ float s[4][3072];
  const int w = threadIdx.x >> 6, l = threadIdx.x & 63;
  const size_t t = (size_t)blockIdx.x * 4 + w;
  const bf16_t* src = qkv + t * 3072;
#pragma unroll
  for (int i = 0; i < 6; ++i) {
    int f = (i * 64 + l) * 8;
    bf16x8 v = *reinterpret_cast<const bf16x8*>(&src[f]);
#pragma unroll
    for (int jj = 0; jj < 8; ++jj) s[w][f + jj] = (float)v[jj];
  }
  __syncthreads();

  const int h = l >> 2, ss = l & 3;
  float qr[16];
  const float* qb = &s[w][h * 192 + ss * 16];
#pragma unroll
  for (int d = 0; d < 16; ++d) qr[d] = qb[d];

  float sc[16];
#pragma unroll
  for (int g = 0; g < 16; ++g) {
    const float* kk = &s[w][g * 192 + 64 + ss * 16];
    float p = 0.f;
#pragma unroll
    for (int d = 0; d < 16; ++d) p += qr[d] * kk[d];
    p += __shfl_xor(p, 1);
    p += __shfl_xor(p, 2);
    sc[g] = p * 0.125f;
  }
  float m = sc[0];
#pragma unroll
  for (int g = 1; g < 16; ++g) m = fmaxf(m, sc[g]);
  float sum = 0.f;
#pragma unroll
  for (int g = 0; g < 16; ++g) { sc[g] = __expf(sc[g] - m); sum += sc[g]; }
  float inv = 1.f / sum;

  float o[16] = {};
#pragma unroll
  for (int g = 0; g < 16; ++g) {
    float a = sc[g] * inv;
    const float* vv = &s[w][g * 192 + 128 + ss * 16];
#pragma unroll
    for (int d = 0; d < 16; ++d) o[d] += a * vv[d];
  }
  union { bf16_t b[16]; uint4 u[2]; } pk;
#pragma unroll
  for (int d = 0; d < 16; ++d) pk.b[d] = (bf16_t)o[d];
  uint4* dst = reinterpret_cast<uint4*>(out + t * 1024 + h * 64 + ss * 16);
  dst[0] = pk.u[0];
  dst[1] = pk.u[1];
}

// ---------------- launch ----------------
extern "C" void kernel_launch(void* const* d_in, const int* in_sizes, int n_in,
                              void* d_out, int out_size, void* d_ws, size_t ws_size,
                              hipStream_t stream) {
  const float* x     = (const float*)d_in[0];  // [8,2048,1024]
  const float* Wqkv  = (const float*)d_in[1];  // [3072,1024]
  const float* Wproj = (const float*)d_in[2];  // [1024,1024]
  const float* bproj = (const float*)d_in[3];  // [1024]
  float* out = (float*)d_out;

  const int M = 8 * 2048;   // 16384 tokens
  const int DM = 1024;
  const int F = 3072;

  char* ws = (char*)d_ws;
  bf16_t* xb     = (bf16_t*)ws;  ws += (size_t)M * DM * 2;
  bf16_t* wqkvb  = (bf16_t*)ws;  ws += (size_t)F * DM * 2;
  bf16_t* wprojb = (bf16_t*)ws;  ws += (size_t)DM * DM * 2;
  bf16_t* qkvb   = (bf16_t*)ws;  ws += (size_t)M * F * 2;
  bf16_t* attnb  = (bf16_t*)ws;

  cast_f32_bf16<<<2048, 256, 0, stream>>>(x, xb, M * DM / 4);
  cast_f32_bf16<<<512, 256, 0, stream>>>(Wqkv, wqkvb, F * DM / 4);
  cast_f32_bf16<<<256, 256, 0, stream>>>(Wproj, wprojb, DM * DM / 4);

  // GEMM1: [16384,1024] x [3072,1024]^T -> bf16 [16384,3072]
  gemm_pipe<true><<<(M / 256) * (F / 128), 512, 0, stream>>>(
      xb, wqkvb, (void*)qkvb, nullptr, F, M / 256);

  attn_heads<<<M / 4, 256, 0, stream>>>(qkvb, attnb);

  // GEMM2: [16384,1024] x [1024,1024]^T -> f32 [16384,1024] + bias
  gemm_pipe<false><<<(M / 256) * (DM / 128), 512, 0, stream>>>(
      attnb, wprojb, (void*)out, bproj, DM, M / 256);
}

// Round 3
// 244.049 us; speedup vs baseline: 1.1668x; 1.1668x over previous
//
#include <hip/hip_runtime.h>
#include <stdint.h>

typedef __bf16 bf16_t;
typedef __bf16 bf16x8 __attribute__((ext_vector_type(8)));
typedef float f32x4 __attribute__((ext_vector_type(4)));

// async global->LDS, 16B per lane; LDS dest is wave-uniform base + lane*16
__device__ __forceinline__ void gload_lds16(const void* g, void* l) {
  __builtin_amdgcn_global_load_lds(
      (const __attribute__((address_space(1))) uint32_t*)g,
      (__attribute__((address_space(3))) uint32_t*)l, 16, 0, 0);
}

// ---------------- cast f32 -> bf16 (vectorized) ----------------
__global__ void cast_f32_bf16(const float* __restrict__ in,
                              bf16_t* __restrict__ out, int n4) {
  int i = blockIdx.x * blockDim.x + threadIdx.x;
  int stride = gridDim.x * blockDim.x;
  for (int idx = i; idx < n4; idx += stride) {
    float4 v = reinterpret_cast<const float4*>(in)[idx];
    union { bf16_t b[4]; uint2 u; } pk;
    pk.b[0] = (bf16_t)v.x; pk.b[1] = (bf16_t)v.y;
    pk.b[2] = (bf16_t)v.z; pk.b[3] = (bf16_t)v.w;
    reinterpret_cast<uint2*>(out)[idx] = pk.u;
  }
}

// ---------------- pipelined GEMM: C[M][N] = A[M][K] * B[N][K]^T (+bias) -----
// BM=BN=256, BK=32, K=1024 (NT=32). 8 waves (2M x 4N), wave tile 128x64 =
// 8x4 frags of 16x16x32 bf16 MFMA. 4-slot LDS ring (2x 32KB+32KB = 128KB),
// staged 3 tiles ahead, steady-state s_waitcnt vmcnt(8) (counted, never 0
// mid-loop), one raw s_barrier per K-tile, setprio around MFMA cluster.
// LDS [r][32k] chunk-swizzled: LDS[r][c] = G[r][c ^ (r&3)] (16B chunks);
// applied as inverse-swizzled global source + swizzled ds_read (both sides).
// Grid walk: XCD x owns bx in [x*8, x*8+8) (A-slab 4MB = its L2), bx-fast.
template <bool BF16_OUT>
__global__ __launch_bounds__(512, 2)
void gemm_pipe(const bf16_t* __restrict__ A, const bf16_t* __restrict__ B,
               void* __restrict__ Cout, const float* __restrict__ bias,
               int N) {
  constexpr int K = 1024, NT = 32;
  __shared__ bf16_t Al[4][256 * 32];  // 4 x 16KB
  __shared__ bf16_t Bl[4][256 * 32];  // 4 x 16KB

  const int tid = threadIdx.x;
  const int l = tid & 63, w = tid >> 6;
  const int wm = w >> 2, wn = w & 3;

  // XCD-slab walk: xcd = bid%8 owns bx slab, bx-fast / by-slow within slab.
  const int bid = blockIdx.x;
  const int xcd = bid & 7;
  const int idx = bid >> 3;
  const int bx = xcd * 8 + (idx & 7);  // nbx = 64 (M = 16384)
  const int by = idx >> 3;
  const int m0 = bx * 256, n0 = by * 256;

  // ---- staging: per STAGE, 4 issues of 8KB (A rows 0-127,128-255; B same).
  // thread t covers row = t/4, lds chunk = t&3, global chunk = (t&3)^(row&3)
  const int ra = tid >> 2;
  const int ca = ((tid & 3) ^ (ra & 3)) * 8;  // pre-swizzled global k elems
  const bf16_t* pA0 = A + (size_t)(m0 +   0 + ra) * K + ca;
  const bf16_t* pA1 = A + (size_t)(m0 + 128 + ra) * K + ca;
  const bf16_t* pB0 = B + (size_t)(n0 +   0 + ra) * K + ca;
  const bf16_t* pB1 = B + (size_t)(n0 + 128 + ra) * K + ca;
  const int wb = w * 512;  // wave's 1KB segment (elems) within an 8KB issue

#define STAGE(t_, s_) do {                          \
    const int kt_ = (t_) * 32;                      \
    gload_lds16(pA0 + kt_, &Al[s_][wb]);            \
    gload_lds16(pA1 + kt_, &Al[s_][4096 + wb]);     \
    gload_lds16(pB0 + kt_, &Bl[s_][wb]);            \
    gload_lds16(pB1 + kt_, &Bl[s_][4096 + wb]);     \
  } while (0)

  // ---- fragment reads: row = base + (l&15) + f*16, so row&3 == l&3 ----
  const int abase = (wm * 128 + (l & 15)) * 32;
  const int bbase = (wn * 64 + (l & 15)) * 32;
  const int ck = (((l >> 4) ^ (l & 3))) * 8;  // swizzled k-chunk (elems)

  f32x4 acc[8][4] = {};

  STAGE(0, 0);
  STAGE(1, 1);
  STAGE(2, 2);

  int slot = 0;
  for (int t = 0; t < NT; ++t) {
    // counted wait: oldest STAGE (tile t, 4 loads) done; newer ones in flight
    if (t < NT - 2)       asm volatile("s_waitcnt vmcnt(8)" ::: "memory");
    else if (t == NT - 2) asm volatile("s_waitcnt vmcnt(4)" ::: "memory");
    else                  asm volatile("s_waitcnt vmcnt(0)" ::: "memory");
    __builtin_amdgcn_s_barrier();
    asm volatile("" ::: "memory");
    if (t + 3 < NT) {
      int s3 = (slot + 3) & 3;
      STAGE(t + 3, s3);  // slot read at tile t-1: drained before this barrier
    }
    const bf16_t* As = Al[slot];
    const bf16_t* Bs = Bl[slot];
    bf16x8 af[8], bfr[4];
#pragma unroll
    for (int i = 0; i < 8; ++i)
      af[i] = *reinterpret_cast<const bf16x8*>(&As[abase + i * 512 + ck]);
#pragma unroll
    for (int j = 0; j < 4; ++j)
      bfr[j] = *reinterpret_cast<const bf16x8*>(&Bs[bbase + j * 512 + ck]);
    __builtin_amdgcn_s_setprio(1);
#pragma unroll
    for (int i = 0; i < 8; ++i)
#pragma unroll
      for (int j = 0; j < 4; ++j)
        acc[i][j] = __builtin_amdgcn_mfma_f32_16x16x32_bf16(af[i], bfr[j],
                                                            acc[i][j], 0, 0, 0);
    __builtin_amdgcn_s_setprio(0);
    slot = (slot + 1) & 3;
  }
#undef STAGE

  // ---- epilogue: C/D layout col = lane&15, row = (lane>>4)*4 + reg ----
  const int r0 = m0 + wm * 128 + (l >> 4) * 4;
  const int c0 = n0 + wn * 64 + (l & 15);
  if (BF16_OUT) {
    bf16_t* C = (bf16_t*)Cout;
#pragma unroll
    for (int i = 0; i < 8; ++i)
#pragma unroll
      for (int j = 0; j < 4; ++j)
#pragma unroll
        for (int r = 0; r < 4; ++r)
          C[(size_t)(r0 + i * 16 + r) * N + (c0 + j * 16)] = (bf16_t)acc[i][j][r];
  } else {
    float* C = (float*)Cout;
#pragma unroll
    for (int i = 0; i < 8; ++i)
#pragma unroll
      for (int j = 0; j < 4; ++j)
#pragma unroll
        for (int r = 0; r < 4; ++r)
          C[(size_t)(r0 + i * 16 + r) * N + (c0 + j * 16)] =
              acc[i][j][r] + bias[c0 + j * 16];
  }
}

// ---------------- per-token head-attention ----------------
__global__ __launch_bounds__(256)
void attn_heads(const bf16_t* __restrict__ qkv, bf16_t* __restrict__ out) {
  __shared__ float s[4][3072];
  const int w = threadIdx.x >> 6, l = threadIdx.x & 63;
  const size_t t = (size_t)blockIdx.x * 4 + w;
  const bf16_t* src = qkv + t * 3072;
#pragma unroll
  for (int i = 0; i < 6; ++i) {
    int f = (i * 64 + l) * 8;
    bf16x8 v = *reinterpret_cast<const bf16x8*>(&src[f]);
#pragma unroll
    for (int jj = 0; jj < 8; ++jj) s[w][f + jj] = (float)v[jj];
  }
  __syncthreads();

  const int h = l >> 2, ss = l & 3;
  float qr[16];
  const float* qb = &s[w][h * 192 + ss * 16];
#pragma unroll
  for (int d = 0; d < 16; ++d) qr[d] = qb[d];

  float sc[16];
#pragma unroll
  for (int g = 0; g < 16; ++g) {
    const float* kk = &s[w][g * 192 + 64 + ss * 16];
    float p = 0.f;
#pragma unroll
    for (int d = 0; d < 16; ++d) p += qr[d] * kk[d];
    p += __shfl_xor(p, 1);
    p += __shfl_xor(p, 2);
    sc[g] = p * 0.125f;
  }
  float m = sc[0];
#pragma unroll
  for (int g = 1; g < 16; ++g) m = fmaxf(m, sc[g]);
  float sum = 0.f;
#pragma unroll
  for (int g = 0; g < 16; ++g) { sc[g] = __expf(sc[g] - m); sum += sc[g]; }
  float inv = 1.f / sum;

  float o[16] = {};
#pragma unroll
  for (int g = 0; g < 16; ++g) {
    float a = sc[g] * inv;
    const float* vv = &s[w][g * 192 + 128 + ss * 16];
#pragma unroll
    for (int d = 0; d < 16; ++d) o[d] += a * vv[d];
  }
  union { bf16_t b[16]; uint4 u[2]; } pk;
#pragma unroll
  for (int d = 0; d < 16; ++d) pk.b[d] = (bf16_t)o[d];
  uint4* dst = reinterpret_cast<uint4*>(out + t * 1024 + h * 64 + ss * 16);
  dst[0] = pk.u[0];
  dst[1] = pk.u[1];
}

// ---------------- launch ----------------
extern "C" void kernel_launch(void* const* d_in, const int* in_sizes, int n_in,
                              void* d_out, int out_size, void* d_ws, size_t ws_size,
                              hipStream_t stream) {
  const float* x     = (const float*)d_in[0];  // [8,2048,1024]
  const float* Wqkv  = (const float*)d_in[1];  // [3072,1024]
  const float* Wproj = (const float*)d_in[2];  // [1024,1024]
  const float* bproj = (const float*)d_in[3];  // [1024]
  float* out = (float*)d_out;

  const int M = 8 * 2048;   // 16384 tokens -> 64 bx blocks of 256
  const int DM = 1024;
  const int F = 3072;

  char* ws = (char*)d_ws;
  bf16_t* xb     = (bf16_t*)ws;  ws += (size_t)M * DM * 2;
  bf16_t* wqkvb  = (bf16_t*)ws;  ws += (size_t)F * DM * 2;
  bf16_t* wprojb = (bf16_t*)ws;  ws += (size_t)DM * DM * 2;
  bf16_t* qkvb   = (bf16_t*)ws;  ws += (size_t)M * F * 2;
  bf16_t* attnb  = (bf16_t*)ws;

  cast_f32_bf16<<<2048, 256, 0, stream>>>(x, xb, M * DM / 4);
  cast_f32_bf16<<<512, 256, 0, stream>>>(Wqkv, wqkvb, F * DM / 4);
  cast_f32_bf16<<<256, 256, 0, stream>>>(Wproj, wprojb, DM * DM / 4);

  // GEMM1: [16384,1024] x [3072,1024]^T -> bf16 [16384,3072]
  gemm_pipe<true><<<(M / 256) * (F / 256), 512, 0, stream>>>(
      xb, wqkvb, (void*)qkvb, nullptr, F);

  attn_heads<<<M / 4, 256, 0, stream>>>(qkvb, attnb);

  // GEMM2: [16384,1024] x [1024,1024]^T -> f32 [16384,1024] + bias
  gemm_pipe<false><<<(M / 256) * (DM / 256), 512, 0, stream>>>(
      attnb, wprojb, (void*)out, bproj, DM);
}

// Round 4
// 238.582 us; speedup vs baseline: 1.1935x; 1.0229x over previous
//
#include <hip/hip_runtime.h>
#include <stdint.h>

typedef __bf16 bf16_t;
typedef __bf16 bf16x8 __attribute__((ext_vector_type(8)));
typedef float f32x4 __attribute__((ext_vector_type(4)));

// async global->LDS, 16B per lane; LDS dest is wave-uniform base + lane*16
__device__ __forceinline__ void gload_lds16(const void* g, void* l) {
  __builtin_amdgcn_global_load_lds(
      (const __attribute__((address_space(1))) uint32_t*)g,
      (__attribute__((address_space(3))) uint32_t*)l, 16, 0, 0);
}

// ---------------- fused cast f32 -> bf16 for 3 buffers ----------------
__global__ void cast3_f32_bf16(const float* __restrict__ a, bf16_t* __restrict__ ao, int n4a,
                               const float* __restrict__ b, bf16_t* __restrict__ bo, int n4b,
                               const float* __restrict__ c, bf16_t* __restrict__ co, int n4c) {
  int i = blockIdx.x * blockDim.x + threadIdx.x;
  int stride = gridDim.x * blockDim.x;
  int total = n4a + n4b + n4c;
  for (int idx = i; idx < total; idx += stride) {
    const float* src; bf16_t* dst; int j = idx;
    if (j < n4a) { src = a; dst = ao; }
    else if ((j -= n4a) < n4b) { src = b; dst = bo; }
    else { j -= n4b; src = c; dst = co; }
    float4 v = reinterpret_cast<const float4*>(src)[j];
    union { bf16_t b[4]; uint2 u; } pk;
    pk.b[0] = (bf16_t)v.x; pk.b[1] = (bf16_t)v.y;
    pk.b[2] = (bf16_t)v.z; pk.b[3] = (bf16_t)v.w;
    reinterpret_cast<uint2*>(dst)[j] = pk.u;
  }
}

// ---------------- pipelined GEMM: C[M][N] = A[M][K] * B[N][K]^T (+bias) -----
// BM=BN=256, BK=32, K=1024 (NT=32). 8 waves (2M x 4N), wave tile 128x64 =
// 8x4 frags of 16x16x32 bf16 MFMA. 4-slot LDS ring (128KB), staged 3 ahead,
// steady-state s_waitcnt vmcnt(8) (counted, never 0 mid-loop), one raw
// s_barrier per K-tile, setprio around MFMA cluster.
// LDS [r][32k] 16B-chunk swizzle: LDS[r][c] = G[r][c ^ ((r>>1)&3)].
//   (f(r) must avoid row bit 0 - that bit already selects the bank half via
//    the 64B row stride. With f=(r>>1)&3 the read residue (q&1)*4+(s^f)
//    covers all 8 bank groups exactly 2x per quarter-wave -> conflict-free.)
// Grid walk: XCD x owns bx slab [x*8, x*8+8) (A-slab 4MB = its L2), bx-fast.
template <bool BF16_OUT>
__global__ __launch_bounds__(512, 2)
void gemm_pipe(const bf16_t* __restrict__ A, const bf16_t* __restrict__ B,
               void* __restrict__ Cout, const float* __restrict__ bias,
               int N) {
  constexpr int K = 1024, NT = 32;
  __shared__ bf16_t Al[4][256 * 32];  // 4 x 16KB
  __shared__ bf16_t Bl[4][256 * 32];  // 4 x 16KB

  const int tid = threadIdx.x;
  const int l = tid & 63, w = tid >> 6;
  const int wm = w >> 2, wn = w & 3;

  const int bid = blockIdx.x;
  const int xcd = bid & 7;
  const int idx = bid >> 3;
  const int bx = xcd * 8 + (idx & 7);  // nbx = 64 (M = 16384)
  const int by = idx >> 3;
  const int m0 = bx * 256, n0 = by * 256;

  // ---- staging: per STAGE, 4 issues of 8KB. thread t: row = t>>2,
  // lds chunk = t&3, global chunk = (t&3) ^ ((row>>1)&3) = (t&3)^((t>>3)&3)
  const int ra = tid >> 2;
  const int ca = ((tid & 3) ^ ((tid >> 3) & 3)) * 8;  // pre-swizzled k elems
  const bf16_t* pA0 = A + (size_t)(m0 +   0 + ra) * K + ca;
  const bf16_t* pA1 = A + (size_t)(m0 + 128 + ra) * K + ca;
  const bf16_t* pB0 = B + (size_t)(n0 +   0 + ra) * K + ca;
  const bf16_t* pB1 = B + (size_t)(n0 + 128 + ra) * K + ca;
  const int wb = w * 512;  // wave's 1KB segment (elems) within an 8KB issue

#define STAGE(t_, s_) do {                          \
    const int kt_ = (t_) * 32;                      \
    gload_lds16(pA0 + kt_, &Al[s_][wb]);            \
    gload_lds16(pA1 + kt_, &Al[s_][4096 + wb]);     \
    gload_lds16(pB0 + kt_, &Bl[s_][wb]);            \
    gload_lds16(pB1 + kt_, &Bl[s_][4096 + wb]);     \
  } while (0)

  // ---- fragment reads: row = base + (l&15) + 16i (bases mult of 16), so
  // (row>>1)&3 = (l>>1)&3 ; lds chunk = (l>>4) ^ ((l>>1)&3)
  const int abase = (wm * 128 + (l & 15)) * 32;
  const int bbase = (wn * 64 + (l & 15)) * 32;
  const int ck = ((l >> 4) ^ ((l >> 1) & 3)) * 8;  // swizzled k-chunk (elems)

  f32x4 acc[8][4] = {};

  STAGE(0, 0);
  STAGE(1, 1);
  STAGE(2, 2);

  int slot = 0;
  for (int t = 0; t < NT; ++t) {
    // counted wait: oldest STAGE (tile t, 4 loads) done; newer ones in flight
    if (t < NT - 2)       asm volatile("s_waitcnt vmcnt(8)" ::: "memory");
    else if (t == NT - 2) asm volatile("s_waitcnt vmcnt(4)" ::: "memory");
    else                  asm volatile("s_waitcnt vmcnt(0)" ::: "memory");
    __builtin_amdgcn_s_barrier();
    asm volatile("" ::: "memory");
    if (t + 3 < NT) {
      int s3 = (slot + 3) & 3;
      STAGE(t + 3, s3);  // slot read at tile t-1: drained before this barrier
    }
    const bf16_t* As = Al[slot];
    const bf16_t* Bs = Bl[slot];
    bf16x8 af[8], bfr[4];
#pragma unroll
    for (int i = 0; i < 8; ++i)
      af[i] = *reinterpret_cast<const bf16x8*>(&As[abase + i * 512 + ck]);
#pragma unroll
    for (int j = 0; j < 4; ++j)
      bfr[j] = *reinterpret_cast<const bf16x8*>(&Bs[bbase + j * 512 + ck]);
    __builtin_amdgcn_s_setprio(1);
#pragma unroll
    for (int i = 0; i < 8; ++i)
#pragma unroll
      for (int j = 0; j < 4; ++j)
        acc[i][j] = __builtin_amdgcn_mfma_f32_16x16x32_bf16(af[i], bfr[j],
                                                            acc[i][j], 0, 0, 0);
    __builtin_amdgcn_s_setprio(0);
    slot = (slot + 1) & 3;
  }
#undef STAGE

  // ---- epilogue: C/D layout col = lane&15, row = (lane>>4)*4 + reg ----
  const int r0 = m0 + wm * 128 + (l >> 4) * 4;
  const int c0 = n0 + wn * 64 + (l & 15);
  if (BF16_OUT) {
    bf16_t* C = (bf16_t*)Cout;
#pragma unroll
    for (int i = 0; i < 8; ++i)
#pragma unroll
      for (int j = 0; j < 4; ++j)
#pragma unroll
        for (int r = 0; r < 4; ++r)
          C[(size_t)(r0 + i * 16 + r) * N + (c0 + j * 16)] = (bf16_t)acc[i][j][r];
  } else {
    float* C = (float*)Cout;
#pragma unroll
    for (int i = 0; i < 8; ++i)
#pragma unroll
      for (int j = 0; j < 4; ++j)
#pragma unroll
        for (int r = 0; r < 4; ++r)
          C[(size_t)(r0 + i * 16 + r) * N + (c0 + j * 16)] =
              acc[i][j][r] + bias[c0 + j * 16];
  }
}

// ---------------- per-token head-attention ----------------
__global__ __launch_bounds__(256)
void attn_heads(const bf16_t* __restrict__ qkv, bf16_t* __restrict__ out) {
  __shared__ float s[4][3072];
  const int w = threadIdx.x >> 6, l = threadIdx.x & 63;
  const size_t t = (size_t)blockIdx.x * 4 + w;
  const bf16_t* src = qkv + t * 3072;
#pragma unroll
  for (int i = 0; i < 6; ++i) {
    int f = (i * 64 + l) * 8;
    bf16x8 v = *reinterpret_cast<const bf16x8*>(&src[f]);
#pragma unroll
    for (int jj = 0; jj < 8; ++jj) s[w][f + jj] = (float)v[jj];
  }
  __syncthreads();

  const int h = l >> 2, ss = l & 3;
  float qr[16];
  const float* qb = &s[w][h * 192 + ss * 16];
#pragma unroll
  for (int d = 0; d < 16; ++d) qr[d] = qb[d];

  float sc[16];
#pragma unroll
  for (int g = 0; g < 16; ++g) {
    const float* kk = &s[w][g * 192 + 64 + ss * 16];
    float p = 0.f;
#pragma unroll
    for (int d = 0; d < 16; ++d) p += qr[d] * kk[d];
    p += __shfl_xor(p, 1);
    p += __shfl_xor(p, 2);
    sc[g] = p * 0.125f;
  }
  float m = sc[0];
#pragma unroll
  for (int g = 1; g < 16; ++g) m = fmaxf(m, sc[g]);
  float sum = 0.f;
#pragma unroll
  for (int g = 0; g < 16; ++g) { sc[g] = __expf(sc[g] - m); sum += sc[g]; }
  float inv = 1.f / sum;

  float o[16] = {};
#pragma unroll
  for (int g = 0; g < 16; ++g) {
    float a = sc[g] * inv;
    const float* vv = &s[w][g * 192 + 128 + ss * 16];
#pragma unroll
    for (int d = 0; d < 16; ++d) o[d] += a * vv[d];
  }
  union { bf16_t b[16]; uint4 u[2]; } pk;
#pragma unroll
  for (int d = 0; d < 16; ++d) pk.b[d] = (bf16_t)o[d];
  uint4* dst = reinterpret_cast<uint4*>(out + t * 1024 + h * 64 + ss * 16);
  dst[0] = pk.u[0];
  dst[1] = pk.u[1];
}

// ---------------- launch ----------------
extern "C" void kernel_launch(void* const* d_in, const int* in_sizes, int n_in,
                              void* d_out, int out_size, void* d_ws, size_t ws_size,
                              hipStream_t stream) {
  const float* x     = (const float*)d_in[0];  // [8,2048,1024]
  const float* Wqkv  = (const float*)d_in[1];  // [3072,1024]
  const float* Wproj = (const float*)d_in[2];  // [1024,1024]
  const float* bproj = (const float*)d_in[3];  // [1024]
  float* out = (float*)d_out;

  const int M = 8 * 2048;   // 16384 tokens -> 64 bx blocks of 256
  const int DM = 1024;
  const int F = 3072;

  char* ws = (char*)d_ws;
  bf16_t* xb     = (bf16_t*)ws;  ws += (size_t)M * DM * 2;
  bf16_t* wqkvb  = (bf16_t*)ws;  ws += (size_t)F * DM * 2;
  bf16_t* wprojb = (bf16_t*)ws;  ws += (size_t)DM * DM * 2;
  bf16_t* qkvb   = (bf16_t*)ws;  ws += (size_t)M * F * 2;
  bf16_t* attnb  = (bf16_t*)ws;

  cast3_f32_bf16<<<2048, 256, 0, stream>>>(x, xb, M * DM / 4,
                                           Wqkv, wqkvb, F * DM / 4,
                                           Wproj, wprojb, DM * DM / 4);

  // GEMM1: [16384,1024] x [3072,1024]^T -> bf16 [16384,3072]
  gemm_pipe<true><<<(M / 256) * (F / 256), 512, 0, stream>>>(
      xb, wqkvb, (void*)qkvb, nullptr, F);

  attn_heads<<<M / 4, 256, 0, stream>>>(qkvb, attnb);

  // GEMM2: [16384,1024] x [1024,1024]^T -> f32 [16384,1024] + bias
  gemm_pipe<false><<<(M / 256) * (DM / 256), 512, 0, stream>>>(
      attnb, wprojb, (void*)out, bproj, DM);
}

// Round 5
// 214.865 us; speedup vs baseline: 1.3253x; 1.1104x over previous
//
#include <hip/hip_runtime.h>
#include <stdint.h>

typedef __bf16 bf16_t;
typedef __bf16 bf16x8 __attribute__((ext_vector_type(8)));
typedef float f32x4 __attribute__((ext_vector_type(4)));

// async global->LDS, 16B per lane; LDS dest is wave-uniform base + lane*16
__device__ __forceinline__ void gload_lds16(const void* g, void* l) {
  __builtin_amdgcn_global_load_lds(
      (const __attribute__((address_space(1))) uint32_t*)g,
      (__attribute__((address_space(3))) uint32_t*)l, 16, 0, 0);
}

// ---------------- fused cast f32 -> bf16 for 3 buffers ----------------
__global__ void cast3_f32_bf16(const float* __restrict__ a, bf16_t* __restrict__ ao, int n4a,
                               const float* __restrict__ b, bf16_t* __restrict__ bo, int n4b,
                               const float* __restrict__ c, bf16_t* __restrict__ co, int n4c) {
  int i = blockIdx.x * blockDim.x + threadIdx.x;
  int stride = gridDim.x * blockDim.x;
  int total = n4a + n4b + n4c;
  for (int idx = i; idx < total; idx += stride) {
    const float* src; bf16_t* dst; int j = idx;
    if (j < n4a) { src = a; dst = ao; }
    else if ((j -= n4a) < n4b) { src = b; dst = bo; }
    else { j -= n4b; src = c; dst = co; }
    float4 v = reinterpret_cast<const float4*>(src)[j];
    union { bf16_t b[4]; uint2 u; } pk;
    pk.b[0] = (bf16_t)v.x; pk.b[1] = (bf16_t)v.y;
    pk.b[2] = (bf16_t)v.z; pk.b[3] = (bf16_t)v.w;
    reinterpret_cast<uint2*>(dst)[j] = pk.u;
  }
}

// ---------------- 8-phase pipelined GEMM: C = A * B^T (+bias) ----------------
// BM=BN=256, BK=32, K=1024 (NT=32). 8 waves (2M x 4N), wave tile 128x64 =
// 8x4 frags of 16x16x32 bf16 MFMA. 4-slot LDS ring (128KB), staged 3 ahead.
// m201-style phase rhythm, 2 phases per K-tile (= 8 phases / 128 K):
//   P0: ds_read af[0..3]+bfr[0..3] | stage A(t+3) | bar | lgkm0 | 16 MFMA | bar
//   P1: ds_read af[4..7]           | stage B(t+3) | bar | lgkm0 | 16 MFMA
//       | counted vmcnt (8 steady; 4/0 only in last-2-tile epilogue) | bar
// LDS 16B-chunk swizzle: LDS[r][c] = G[r][c ^ ((r>>1)&3)] (both sides; row
// bit0 already selects bank half -> conflict-free, verified 0 conflicts).
// Grid: XCD x owns bx slab [x*8, x*8+8) (A-slab 4MB = its L2), bx-fast.
template <bool BF16_OUT>
__global__ __launch_bounds__(512, 2)
void gemm_pipe(const bf16_t* __restrict__ A, const bf16_t* __restrict__ B,
               void* __restrict__ Cout, const float* __restrict__ bias,
               int N) {
  constexpr int K = 1024, NT = 32;
  __shared__ bf16_t Al[4][256 * 32];  // 4 x 16KB
  __shared__ bf16_t Bl[4][256 * 32];  // 4 x 16KB

  const int tid = threadIdx.x;
  const int l = tid & 63, w = tid >> 6;
  const int wm = w >> 2, wn = w & 3;

  const int bid = blockIdx.x;
  const int xcd = bid & 7;
  const int idx = bid >> 3;
  const int bx = xcd * 8 + (idx & 7);  // nbx = 64 (M = 16384)
  const int by = idx >> 3;
  const int m0 = bx * 256, n0 = by * 256;

  // staging: thread t: row = t>>2, lds chunk = t&3, global chunk (t&3)^((t>>3)&3)
  const int ra = tid >> 2;
  const int ca = ((tid & 3) ^ ((tid >> 3) & 3)) * 8;  // pre-swizzled k elems
  const bf16_t* pA0 = A + (size_t)(m0 +   0 + ra) * K + ca;
  const bf16_t* pA1 = A + (size_t)(m0 + 128 + ra) * K + ca;
  const bf16_t* pB0 = B + (size_t)(n0 +   0 + ra) * K + ca;
  const bf16_t* pB1 = B + (size_t)(n0 + 128 + ra) * K + ca;
  const int wb = w * 512;  // wave's 1KB segment (elems) within an 8KB issue

#define STAGE_A(t_, s_) do { const int kt_ = (t_) * 32;          \
    gload_lds16(pA0 + kt_, &Al[s_][wb]);                         \
    gload_lds16(pA1 + kt_, &Al[s_][4096 + wb]); } while (0)
#define STAGE_B(t_, s_) do { const int kt_ = (t_) * 32;          \
    gload_lds16(pB0 + kt_, &Bl[s_][wb]);                         \
    gload_lds16(pB1 + kt_, &Bl[s_][4096 + wb]); } while (0)

  // fragment reads: row = base + (l&15) + 16i -> (row>>1)&3 = (l>>1)&3
  const int abase = (wm * 128 + (l & 15)) * 32;
  const int bbase = (wn * 64 + (l & 15)) * 32;
  const int ck = ((l >> 4) ^ ((l >> 1) & 3)) * 8;  // swizzled k-chunk (elems)

  f32x4 acc[8][4] = {};

  STAGE_A(0, 0); STAGE_B(0, 0);
  STAGE_A(1, 1); STAGE_B(1, 1);
  STAGE_A(2, 2); STAGE_B(2, 2);
  asm volatile("s_waitcnt vmcnt(8)" ::: "memory");  // tile 0 landed
  __builtin_amdgcn_s_barrier();

  for (int t = 0; t < NT; ++t) {
    const int slot = t & 3;
    const int s3 = (t + 3) & 3;
    const bf16_t* As = Al[slot];
    const bf16_t* Bs = Bl[slot];
    bf16x8 af0[4], af1[4], bfr[4];

    // -------- phase 0 --------
#pragma unroll
    for (int i = 0; i < 4; ++i)
      af0[i] = *reinterpret_cast<const bf16x8*>(&As[abase + i * 512 + ck]);
#pragma unroll
    for (int j = 0; j < 4; ++j)
      bfr[j] = *reinterpret_cast<const bf16x8*>(&Bs[bbase + j * 512 + ck]);
    if (t + 3 < NT) STAGE_A(t + 3, s3);  // slot(t-1): reads drained pre-barrier
    __builtin_amdgcn_s_barrier();
    asm volatile("s_waitcnt lgkmcnt(0)" ::: "memory");
    __builtin_amdgcn_sched_barrier(0);
    __builtin_amdgcn_s_setprio(1);
#pragma unroll
    for (int i = 0; i < 4; ++i)
#pragma unroll
      for (int j = 0; j < 4; ++j)
        acc[i][j] = __builtin_amdgcn_mfma_f32_16x16x32_bf16(af0[i], bfr[j],
                                                            acc[i][j], 0, 0, 0);
    __builtin_amdgcn_s_setprio(0);
    __builtin_amdgcn_s_barrier();

    // -------- phase 1 --------
#pragma unroll
    for (int i = 0; i < 4; ++i)
      af1[i] = *reinterpret_cast<const bf16x8*>(&As[abase + (i + 4) * 512 + ck]);
    if (t + 3 < NT) STAGE_B(t + 3, s3);
    __builtin_amdgcn_s_barrier();
    asm volatile("s_waitcnt lgkmcnt(0)" ::: "memory");
    __builtin_amdgcn_sched_barrier(0);
    __builtin_amdgcn_s_setprio(1);
#pragma unroll
    for (int i = 0; i < 4; ++i)
#pragma unroll
      for (int j = 0; j < 4; ++j)
        acc[i + 4][j] = __builtin_amdgcn_mfma_f32_16x16x32_bf16(af1[i], bfr[j],
                                                                acc[i + 4][j], 0, 0, 0);
    __builtin_amdgcn_s_setprio(0);
    // counted vmcnt once per K-tile; 0 only in final-2-tile epilogue
    if (t + 3 < NT)       asm volatile("s_waitcnt vmcnt(8)" ::: "memory");
    else if (t == NT - 3) asm volatile("s_waitcnt vmcnt(4)" ::: "memory");
    else if (t == NT - 2) asm volatile("s_waitcnt vmcnt(0)" ::: "memory");
    __builtin_amdgcn_s_barrier();
  }
#undef STAGE_A
#undef STAGE_B

  // ---- epilogue: C/D layout col = lane&15, row = (lane>>4)*4 + reg ----
  const int r0 = m0 + wm * 128 + (l >> 4) * 4;
  const int c0 = n0 + wn * 64 + (l & 15);
  if (BF16_OUT) {
    bf16_t* C = (bf16_t*)Cout;
#pragma unroll
    for (int i = 0; i < 8; ++i)
#pragma unroll
      for (int j = 0; j < 4; ++j)
#pragma unroll
        for (int r = 0; r < 4; ++r)
          C[(size_t)(r0 + i * 16 + r) * N + (c0 + j * 16)] = (bf16_t)acc[i][j][r];
  } else {
    float* C = (float*)Cout;
#pragma unroll
    for (int i = 0; i < 8; ++i)
#pragma unroll
      for (int j = 0; j < 4; ++j)
#pragma unroll
        for (int r = 0; r < 4; ++r)
          C[(size_t)(r0 + i * 16 + r) * N + (c0 + j * 16)] =
              acc[i][j][r] + bias[c0 + j * 16];
  }
}

// ---------------- per-token head-attention ----------------
__global__ __launch_bounds__(256)
void attn_heads(const bf16_t* __restrict__ qkv, bf16_t* __restrict__ out) {
  __shared__ float s[4][3072];
  const int w = threadIdx.x >> 6, l = threadIdx.x & 63;
  const size_t t = (size_t)blockIdx.x * 4 + w;
  const bf16_t* src = qkv + t * 3072;
#pragma unroll
  for (int i = 0; i < 6; ++i) {
    int f = (i * 64 + l) * 8;
    bf16x8 v = *reinterpret_cast<const bf16x8*>(&src[f]);
#pragma unroll
    for (int jj = 0; jj < 8; ++jj) s[w][f + jj] = (float)v[jj];
  }
  __syncthreads();

  const int h = l >> 2, ss = l & 3;
  float qr[16];
  const float* qb = &s[w][h * 192 + ss * 16];
#pragma unroll
  for (int d = 0; d < 16; ++d) qr[d] = qb[d];

  float sc[16];
#pragma unroll
  for (int g = 0; g < 16; ++g) {
    const float* kk = &s[w][g * 192 + 64 + ss * 16];
    float p = 0.f;
#pragma unroll
    for (int d = 0; d < 16; ++d) p += qr[d] * kk[d];
    p += __shfl_xor(p, 1);
    p += __shfl_xor(p, 2);
    sc[g] = p * 0.125f;
  }
  float m = sc[0];
#pragma unroll
  for (int g = 1; g < 16; ++g) m = fmaxf(m, sc[g]);
  float sum = 0.f;
#pragma unroll
  for (int g = 0; g < 16; ++g) { sc[g] = __expf(sc[g] - m); sum += sc[g]; }
  float inv = 1.f / sum;

  float o[16] = {};
#pragma unroll
  for (int g = 0; g < 16; ++g) {
    float a = sc[g] * inv;
    const float* vv = &s[w][g * 192 + 128 + ss * 16];
#pragma unroll
    for (int d = 0; d < 16; ++d) o[d] += a * vv[d];
  }
  union { bf16_t b[16]; uint4 u[2]; } pk;
#pragma unroll
  for (int d = 0; d < 16; ++d) pk.b[d] = (bf16_t)o[d];
  uint4* dst = reinterpret_cast<uint4*>(out + t * 1024 + h * 64 + ss * 16);
  dst[0] = pk.u[0];
  dst[1] = pk.u[1];
}

// ---------------- launch ----------------
extern "C" void kernel_launch(void* const* d_in, const int* in_sizes, int n_in,
                              void* d_out, int out_size, void* d_ws, size_t ws_size,
                              hipStream_t stream) {
  const float* x     = (const float*)d_in[0];  // [8,2048,1024]
  const float* Wqkv  = (const float*)d_in[1];  // [3072,1024]
  const float* Wproj = (const float*)d_in[2];  // [1024,1024]
  const float* bproj = (const float*)d_in[3];  // [1024]
  float* out = (float*)d_out;

  const int M = 8 * 2048;   // 16384 tokens -> 64 bx blocks of 256
  const int DM = 1024;
  const int F = 3072;

  char* ws = (char*)d_ws;
  bf16_t* xb     = (bf16_t*)ws;  ws += (size_t)M * DM * 2;
  bf16_t* wqkvb  = (bf16_t*)ws;  ws += (size_t)F * DM * 2;
  bf16_t* wprojb = (bf16_t*)ws;  ws += (size_t)DM * DM * 2;
  bf16_t* qkvb   = (bf16_t*)ws;  ws += (size_t)M * F * 2;
  bf16_t* attnb  = (bf16_t*)ws;

  cast3_f32_bf16<<<2048, 256, 0, stream>>>(x, xb, M * DM / 4,
                                           Wqkv, wqkvb, F * DM / 4,
                                           Wproj, wprojb, DM * DM / 4);

  // GEMM1: [16384,1024] x [3072,1024]^T -> bf16 [16384,3072]
  gemm_pipe<true><<<(M / 256) * (F / 256), 512, 0, stream>>>(
      xb, wqkvb, (void*)qkvb, nullptr, F);

  attn_heads<<<M / 4, 256, 0, stream>>>(qkvb, attnb);

  // GEMM2: [16384,1024] x [1024,1024]^T -> f32 [16384,1024] + bias
  gemm_pipe<false><<<(M / 256) * (DM / 256), 512, 0, stream>>>(
      attnb, wprojb, (void*)out, bproj, DM);
}